// Round 4
// baseline (30.707 us; speedup 1.0000x reference)
//
#include <hip/hip_runtime.h>
#include <hip/hip_fp16.h>

#define BB 16
#define NN 512
#define DD 64
#define ROWS (BB * NN)   // 8192
#define ITILE 8          // targets per k2 block
#define RB 32            // rows per k1 block

static __device__ __forceinline__ __half2 h2bits(unsigned int u) {
    union { unsigned int i; __half2 h; } c; c.i = u; return c.h;
}
static __device__ __forceinline__ unsigned int bits2(__half2 h) {
    union { __half2 h; unsigned int i; } c; c.h = h; return c.i;
}
// acc += sign2 * |u2 + v2|   (3 packed ops: v_pk_add_f16, v_and_b32, v_pk_fma_f16)
static __device__ __forceinline__ __half2 absterm(unsigned int s, unsigned int u,
                                                  unsigned int v, __half2 a) {
    return __hfma2(h2bits(s), __habs2(__hadd2(h2bits(u), h2bits(v))), a);
}

// ---------------- Kernel 1: node transforms ----------------
// xl = x@Wl^T+bl, xr = x@Wr^T+br (fp32 regs); emits packed half2 u'=0.4*att*xr,
// v'=0.4*att*xl, plus axl=att.xl, pxl=Wf.xl, sgnh=sign(att), cterm=bias.Wf+bf
__global__ __launch_bounds__(256, 2) void k1_transform(
    const float* __restrict__ x,
    const float* __restrict__ Wl, const float* __restrict__ bl,
    const float* __restrict__ Wr, const float* __restrict__ br,
    const float* __restrict__ att, const float* __restrict__ bias,
    const float* __restrict__ Wf, const float* __restrict__ bf,
    unsigned int* __restrict__ uh, unsigned int* __restrict__ vh,
    float* __restrict__ axl, float* __restrict__ pxl,
    unsigned int* __restrict__ sgnh, float* __restrict__ cterm)
{
    __shared__ float wt[64][132];      // W^T: wt[k][c], c<64 = Wl col, c>=64 = Wr col
    __shared__ float xst[64][36];      // x^T tile: xst[k][row] (pad 36 -> 16B aligned)
    __shared__ float red[RB][16][2];   // axl/pxl partials

    const int tid = threadIdx.x;
    const int r0 = blockIdx.x * RB;

    // stage W transposed (gathered from L2; one-time)
    #pragma unroll
    for (int t = 0; t < 8; ++t) {
        const int idx = t * 256 + tid;
        const int c   = idx & 127;
        const int k4  = (idx >> 7) << 2;
        const float* src = (c < 64) ? (Wl + c * DD + k4) : (Wr + (c - 64) * DD + k4);
        const float4 v = *reinterpret_cast<const float4*>(src);
        wt[k4 + 0][c] = v.x;
        wt[k4 + 1][c] = v.y;
        wt[k4 + 2][c] = v.z;
        wt[k4 + 3][c] = v.w;
    }
    // stage x transposed (coalesced global read, scatter LDS write)
    #pragma unroll
    for (int p = 0; p < 2; ++p) {
        const int idx = p * 256 + tid;
        const int row = idx >> 4;           // 0..31
        const int k4  = (idx & 15) << 2;
        const float4 v = *reinterpret_cast<const float4*>(&x[(size_t)(r0 + row) * DD + k4]);
        xst[k4 + 0][row] = v.x;
        xst[k4 + 1][row] = v.y;
        xst[k4 + 2][row] = v.z;
        xst[k4 + 3][row] = v.w;
    }
    __syncthreads();

    const int g  = tid & 31;       // col group (4 cols), c0 in [0,128)
    const int rq = tid >> 5;       // row quad 0..7
    const int c0 = g * 4;
    const int ra = rq * 4;
    const bool isL = (c0 < 64);
    const int d0 = c0 & 63;

    const float4 bv = *reinterpret_cast<const float4*>((isL ? bl : br) + d0);
    float acc[4][4];
    #pragma unroll
    for (int r = 0; r < 4; ++r) {
        acc[r][0] = bv.x; acc[r][1] = bv.y; acc[r][2] = bv.z; acc[r][3] = bv.w;
    }

    #pragma unroll 4
    for (int k = 0; k < 64; ++k) {
        const float4 w4 = *reinterpret_cast<const float4*>(&wt[k][c0]);
        const float4 x4 = *reinterpret_cast<const float4*>(&xst[k][ra]);
        acc[0][0] = fmaf(x4.x, w4.x, acc[0][0]);
        acc[0][1] = fmaf(x4.x, w4.y, acc[0][1]);
        acc[0][2] = fmaf(x4.x, w4.z, acc[0][2]);
        acc[0][3] = fmaf(x4.x, w4.w, acc[0][3]);
        acc[1][0] = fmaf(x4.y, w4.x, acc[1][0]);
        acc[1][1] = fmaf(x4.y, w4.y, acc[1][1]);
        acc[1][2] = fmaf(x4.y, w4.z, acc[1][2]);
        acc[1][3] = fmaf(x4.y, w4.w, acc[1][3]);
        acc[2][0] = fmaf(x4.z, w4.x, acc[2][0]);
        acc[2][1] = fmaf(x4.z, w4.y, acc[2][1]);
        acc[2][2] = fmaf(x4.z, w4.z, acc[2][2]);
        acc[2][3] = fmaf(x4.z, w4.w, acc[2][3]);
        acc[3][0] = fmaf(x4.w, w4.x, acc[3][0]);
        acc[3][1] = fmaf(x4.w, w4.y, acc[3][1]);
        acc[3][2] = fmaf(x4.w, w4.z, acc[3][2]);
        acc[3][3] = fmaf(x4.w, w4.w, acc[3][3]);
    }

    const float4 av = *reinterpret_cast<const float4*>(&att[d0]);

    if (isL) {
        const float4 wfv = *reinterpret_cast<const float4*>(&Wf[d0]);
        #pragma unroll
        for (int r = 0; r < 4; ++r) {
            red[ra + r][g][0] = av.x * acc[r][0] + av.y * acc[r][1] + av.z * acc[r][2] + av.w * acc[r][3];
            red[ra + r][g][1] = wfv.x * acc[r][0] + wfv.y * acc[r][1] + wfv.z * acc[r][2] + wfv.w * acc[r][3];
        }
    }

    unsigned int* const dst = isL ? vh : uh;
    #pragma unroll
    for (int r = 0; r < 4; ++r) {
        uint2 pk;
        pk.x = bits2(__floats2half2_rn(0.4f * av.x * acc[r][0], 0.4f * av.y * acc[r][1]));
        pk.y = bits2(__floats2half2_rn(0.4f * av.z * acc[r][2], 0.4f * av.w * acc[r][3]));
        *reinterpret_cast<uint2*>(&dst[(size_t)(r0 + ra + r) * 32 + (d0 >> 1)]) = pk;
    }
    __syncthreads();

    if (tid < 64) {
        const int row = tid >> 1, which = tid & 1;
        float s = 0.f;
        #pragma unroll
        for (int gg = 0; gg < 16; ++gg) s += red[row][gg][which];
        if (which) pxl[r0 + row] = s;
        else       axl[r0 + row] = s;
    }

    if (blockIdx.x == 0) {
        if (tid < 32) {
            const float s0 = (att[2 * tid]     >= 0.f) ? 1.f : -1.f;
            const float s1 = (att[2 * tid + 1] >= 0.f) ? 1.f : -1.f;
            sgnh[tid] = bits2(__floats2half2_rn(s0, s1));
        }
        if (tid == 0) {
            float ct = bf[0];
            #pragma unroll 8
            for (int d = 0; d < DD; ++d) ct = fmaf(bias[d], Wf[d], ct);
            *cterm = ct;
        }
    }
}

// ---------------- Kernel 2: scores + softmax-weighted scalar aggregation ----
// grid: B * (N/ITILE) = 1024 blocks, 512 threads; thread owns source j.
// e'_ij = 0.6*axl_j + sum_d sgn_d * |u'_id + v'_jd|  (0.6*axr_i cancels in softmax)
// u-rows / sgn have blockIdx-only addresses -> wave-uniform -> scalar loads (SGPR),
// no LDS staging needed.
__global__ __launch_bounds__(512, 8) void k2_attn(
    const unsigned int* __restrict__ uh, const unsigned int* __restrict__ vh,
    const float* __restrict__ axl, const float* __restrict__ pxl,
    const unsigned int* __restrict__ sgnh, const float* __restrict__ cterm,
    float* __restrict__ out)
{
    __shared__ float e[ITILE][NN];            // 16 KB

    const int tid = threadIdx.x;
    const int b  = blockIdx.x >> 6;
    const int i0 = (blockIdx.x & 63) * ITILE;
    const int j = tid;
    const size_t rowj = (size_t)b * NN + j;

    uint4 vv[8];
    const uint4* const vb = reinterpret_cast<const uint4*>(&vh[rowj * 32]);
    #pragma unroll
    for (int q = 0; q < 8; ++q) vv[q] = vb[q];

    const uint4* const sb = reinterpret_cast<const uint4*>(sgnh);  // uniform -> SGPR
    const float axlj = 0.6f * axl[rowj];

    #pragma unroll 2
    for (int i = 0; i < ITILE; ++i) {
        const uint4* const ub =
            reinterpret_cast<const uint4*>(&uh[(size_t)(b * NN + i0 + i) * 32]);  // uniform
        __half2 a0 = __float2half2_rn(0.f), a1 = a0;
        #pragma unroll
        for (int q = 0; q < 8; ++q) {
            const uint4 uu = ub[q];
            const uint4 sq = sb[q];
            const uint4 vq = vv[q];
            a0 = absterm(sq.x, uu.x, vq.x, a0);
            a1 = absterm(sq.y, uu.y, vq.y, a1);
            a0 = absterm(sq.z, uu.z, vq.z, a0);
            a1 = absterm(sq.w, uu.w, vq.w, a1);
        }
        const __half2 h = __hadd2(a0, a1);
        e[i][j] = axlj + __low2float(h) + __high2float(h);
    }
    __syncthreads();

    // softmax + weighted scalar dot; wave wv handles target row i = wv
    const int wv = tid >> 6;
    const int lane = tid & 63;

    float pv[8], vals[8];
    #pragma unroll
    for (int k = 0; k < 8; ++k) pv[k] = pxl[(size_t)b * NN + lane + 64 * k];
    #pragma unroll
    for (int k = 0; k < 8; ++k) vals[k] = e[wv][lane + 64 * k];

    float m = vals[0];
    #pragma unroll
    for (int k = 1; k < 8; ++k) m = fmaxf(m, vals[k]);
    #pragma unroll
    for (int mask = 32; mask >= 1; mask >>= 1)
        m = fmaxf(m, __shfl_xor(m, mask));

    float s = 0.f, sp = 0.f;
    #pragma unroll
    for (int k = 0; k < 8; ++k) {
        const float t = __expf(vals[k] - m);
        s += t;
        sp = fmaf(t, pv[k], sp);
    }
    #pragma unroll
    for (int mask = 32; mask >= 1; mask >>= 1) {
        s  += __shfl_xor(s, mask);
        sp += __shfl_xor(sp, mask);
    }
    if (lane == 0)
        out[(size_t)b * NN + i0 + wv] = sp / s + *cterm;
}

extern "C" void kernel_launch(void* const* d_in, const int* in_sizes, int n_in,
                              void* d_out, int out_size, void* d_ws, size_t ws_size,
                              hipStream_t stream) {
    const float* x    = (const float*)d_in[0];
    const float* Wl   = (const float*)d_in[1];
    const float* bl   = (const float*)d_in[2];
    const float* Wr   = (const float*)d_in[3];
    const float* br   = (const float*)d_in[4];
    const float* att  = (const float*)d_in[5];
    const float* bias = (const float*)d_in[6];
    const float* Wf   = (const float*)d_in[7];
    const float* bf   = (const float*)d_in[8];
    float* out = (float*)d_out;

    unsigned char* ws = (unsigned char*)d_ws;
    unsigned int* uh   = (unsigned int*)ws;                 // ROWS*32 u32
    unsigned int* vh   = uh + (size_t)ROWS * 32;            // ROWS*32 u32
    float*        axl  = (float*)(vh + (size_t)ROWS * 32);  // ROWS
    float*        pxl  = axl + ROWS;                        // ROWS
    unsigned int* sgnh = (unsigned int*)(pxl + ROWS);       // 32
    float*        ctp  = (float*)(sgnh + 32);               // 1

    k1_transform<<<ROWS / RB, 256, 0, stream>>>(x, Wl, bl, Wr, br, att, bias, Wf, bf,
                                                uh, vh, axl, pxl, sgnh, ctp);
    k2_attn<<<BB * (NN / ITILE), 512, 0, stream>>>(uh, vh, axl, pxl, sgnh, ctp, out);
}

// Round 5
// 29.723 us; speedup vs baseline: 1.0331x; 1.0331x over previous
//
#include <hip/hip_runtime.h>
#include <hip/hip_fp16.h>

#define BB 16
#define NN 512
#define DD 64
#define ROWS (BB * NN)   // 8192
#define RB 32            // rows per k1 block
#define JCH 32           // j-chunks per sample in k2
#define CHUNK (NN / JCH) // 16 sources per chunk

static __device__ __forceinline__ __half2 h2bits(unsigned int u) {
    union { unsigned int i; __half2 h; } c; c.i = u; return c.h;
}
static __device__ __forceinline__ unsigned int bits2(__half2 h) {
    union { __half2 h; unsigned int i; } c; c.h = h; return c.i;
}
// acc += sign2 * |u2 + v2|   (v_pk_add_f16, v_and_b32, v_pk_fma_f16)
static __device__ __forceinline__ __half2 absterm(unsigned int s, unsigned int u,
                                                  unsigned int v, __half2 a) {
    return __hfma2(h2bits(s), __habs2(__hadd2(h2bits(u), h2bits(v))), a);
}

// ---------------- Kernel 1: node transforms ----------------
// xl = x@Wl^T+bl, xr = x@Wr^T+br (fp32 regs). Emits (chunk-major layout
// [b][q][i], q = uint4 chunk of 8 dims): uh = half2(0.4*att*xr),
// vh = half2(0.4*att*xl); epj = {E, E*pxl} with E = exp(0.6*att.xl),
// pxl = Wf.xl; sgnh = packed sign(att); cterm = bias.Wf + bf.
__global__ __launch_bounds__(256, 2) void k1_transform(
    const float* __restrict__ x,
    const float* __restrict__ Wl, const float* __restrict__ bl,
    const float* __restrict__ Wr, const float* __restrict__ br,
    const float* __restrict__ att, const float* __restrict__ bias,
    const float* __restrict__ Wf, const float* __restrict__ bf,
    unsigned int* __restrict__ uh, unsigned int* __restrict__ vh,
    float2* __restrict__ epj,
    unsigned int* __restrict__ sgnh, float* __restrict__ cterm)
{
    __shared__ float wt[64][132];      // W^T: wt[k][c], c<64 = Wl col, c>=64 = Wr col
    __shared__ float xst[64][36];      // x^T tile: xst[k][row]
    __shared__ float red[RB][16][2];   // axl/pxl partials

    const int tid = threadIdx.x;
    const int r0 = blockIdx.x * RB;

    // stage W transposed (gathered from L2; one-time)
    #pragma unroll
    for (int t = 0; t < 8; ++t) {
        const int idx = t * 256 + tid;
        const int c   = idx & 127;
        const int k4  = (idx >> 7) << 2;
        const float* src = (c < 64) ? (Wl + c * DD + k4) : (Wr + (c - 64) * DD + k4);
        const float4 v = *reinterpret_cast<const float4*>(src);
        wt[k4 + 0][c] = v.x;
        wt[k4 + 1][c] = v.y;
        wt[k4 + 2][c] = v.z;
        wt[k4 + 3][c] = v.w;
    }
    // stage x transposed (coalesced global read)
    #pragma unroll
    for (int p = 0; p < 2; ++p) {
        const int idx = p * 256 + tid;
        const int row = idx >> 4;
        const int k4  = (idx & 15) << 2;
        const float4 v = *reinterpret_cast<const float4*>(&x[(size_t)(r0 + row) * DD + k4]);
        xst[k4 + 0][row] = v.x;
        xst[k4 + 1][row] = v.y;
        xst[k4 + 2][row] = v.z;
        xst[k4 + 3][row] = v.w;
    }
    __syncthreads();

    const int g  = tid & 31;       // col group (4 cols), c0 in [0,128)
    const int rq = tid >> 5;       // row quad 0..7
    const int c0 = g * 4;
    const int ra = rq * 4;
    const bool isL = (c0 < 64);
    const int d0 = c0 & 63;

    const float4 bv = *reinterpret_cast<const float4*>((isL ? bl : br) + d0);
    float acc[4][4];
    #pragma unroll
    for (int r = 0; r < 4; ++r) {
        acc[r][0] = bv.x; acc[r][1] = bv.y; acc[r][2] = bv.z; acc[r][3] = bv.w;
    }

    #pragma unroll 4
    for (int k = 0; k < 64; ++k) {
        const float4 w4 = *reinterpret_cast<const float4*>(&wt[k][c0]);
        const float4 x4 = *reinterpret_cast<const float4*>(&xst[k][ra]);
        acc[0][0] = fmaf(x4.x, w4.x, acc[0][0]);
        acc[0][1] = fmaf(x4.x, w4.y, acc[0][1]);
        acc[0][2] = fmaf(x4.x, w4.z, acc[0][2]);
        acc[0][3] = fmaf(x4.x, w4.w, acc[0][3]);
        acc[1][0] = fmaf(x4.y, w4.x, acc[1][0]);
        acc[1][1] = fmaf(x4.y, w4.y, acc[1][1]);
        acc[1][2] = fmaf(x4.y, w4.z, acc[1][2]);
        acc[1][3] = fmaf(x4.y, w4.w, acc[1][3]);
        acc[2][0] = fmaf(x4.z, w4.x, acc[2][0]);
        acc[2][1] = fmaf(x4.z, w4.y, acc[2][1]);
        acc[2][2] = fmaf(x4.z, w4.z, acc[2][2]);
        acc[2][3] = fmaf(x4.z, w4.w, acc[2][3]);
        acc[3][0] = fmaf(x4.w, w4.x, acc[3][0]);
        acc[3][1] = fmaf(x4.w, w4.y, acc[3][1]);
        acc[3][2] = fmaf(x4.w, w4.z, acc[3][2]);
        acc[3][3] = fmaf(x4.w, w4.w, acc[3][3]);
    }

    const float4 av = *reinterpret_cast<const float4*>(&att[d0]);

    if (isL) {
        const float4 wfv = *reinterpret_cast<const float4*>(&Wf[d0]);
        #pragma unroll
        for (int r = 0; r < 4; ++r) {
            red[ra + r][g][0] = av.x * acc[r][0] + av.y * acc[r][1] + av.z * acc[r][2] + av.w * acc[r][3];
            red[ra + r][g][1] = wfv.x * acc[r][0] + wfv.y * acc[r][1] + wfv.z * acc[r][2] + wfv.w * acc[r][3];
        }
    }

    // chunk-major packed writes: dst[((b*8+q)*512 + i)*4 + slot]
    unsigned int* const dst = isL ? vh : uh;
    const int q    = d0 >> 3;
    const int slot = (d0 & 4) ? 2 : 0;
    const int base = ((r0 >> 9) * 8 + q) * 512 + (r0 & 511);
    #pragma unroll
    for (int r = 0; r < 4; ++r) {
        uint2 pk;
        pk.x = bits2(__floats2half2_rn(0.4f * av.x * acc[r][0], 0.4f * av.y * acc[r][1]));
        pk.y = bits2(__floats2half2_rn(0.4f * av.z * acc[r][2], 0.4f * av.w * acc[r][3]));
        *reinterpret_cast<uint2*>(&dst[(size_t)(base + ra + r) * 4 + slot]) = pk;
    }
    __syncthreads();

    if (tid < RB) {
        float a = 0.f, p = 0.f;
        #pragma unroll
        for (int gg = 0; gg < 16; ++gg) {
            a += red[tid][gg][0];
            p += red[tid][gg][1];
        }
        const float E = __expf(0.6f * a);
        epj[r0 + tid] = make_float2(E, E * p);
    }

    if (blockIdx.x == 0) {
        if (tid < 32) {
            const float s0 = (att[2 * tid]     >= 0.f) ? 1.f : -1.f;
            const float s1 = (att[2 * tid + 1] >= 0.f) ? 1.f : -1.f;
            sgnh[tid] = bits2(__floats2half2_rn(s0, s1));
        }
        if (tid == 0) {
            float ct = bf[0];
            #pragma unroll 8
            for (int d = 0; d < DD; ++d) ct = fmaf(bias[d], Wf[d], ct);
            *cterm = ct;
        }
    }
}

// ---------------- Kernel 2: online-softmax streaming scores ----------------
// grid: B * JCH = 512 blocks, 512 threads; thread owns TARGET i (u-row in regs).
// Streams CHUNK sources j: t = exp(sum_d sgn|u+v|); s += t*Ej; sp += t*Pj.
// No LDS, no barriers, no max (scores bounded ~|1|).
__global__ __launch_bounds__(512, 2) void k2_attn(
    const unsigned int* __restrict__ uh, const unsigned int* __restrict__ vh,
    const float2* __restrict__ epj, const unsigned int* __restrict__ sgnh,
    float2* __restrict__ part)
{
    const int b  = blockIdx.x >> 5;
    const int jc = blockIdx.x & 31;
    const int i  = threadIdx.x;

    uint4 uu[8];
    #pragma unroll
    for (int q = 0; q < 8; ++q)
        uu[q] = *reinterpret_cast<const uint4*>(&uh[(size_t)(((b * 8 + q) << 9) + i) * 4]);

    uint4 sg[8];
    #pragma unroll
    for (int q = 0; q < 8; ++q)
        sg[q] = reinterpret_cast<const uint4*>(sgnh)[q];

    float s = 0.f, sp = 0.f;
    const int j0 = jc * CHUNK;

    #pragma unroll 2
    for (int jj = 0; jj < CHUNK; ++jj) {
        const int j = j0 + jj;
        __half2 a0 = __float2half2_rn(0.f), a1 = a0;
        #pragma unroll
        for (int q = 0; q < 8; ++q) {
            const uint4 vq = *reinterpret_cast<const uint4*>(
                &vh[(size_t)(((b * 8 + q) << 9) + j) * 4]);   // wave-uniform
            a0 = absterm(sg[q].x, uu[q].x, vq.x, a0);
            a1 = absterm(sg[q].y, uu[q].y, vq.y, a1);
            a0 = absterm(sg[q].z, uu[q].z, vq.z, a0);
            a1 = absterm(sg[q].w, uu[q].w, vq.w, a1);
        }
        const __half2 h = __hadd2(a0, a1);
        const float f = __low2float(h) + __high2float(h);
        const float t = __expf(f);
        const float2 ep = epj[(b << 9) + j];                   // wave-uniform
        s  = fmaf(t, ep.x, s);
        sp = fmaf(t, ep.y, sp);
    }
    part[(size_t)(((b << 5) + jc) << 9) + i] = make_float2(s, sp);
}

// ---------------- Kernel 3: combine partials ----------------
__global__ __launch_bounds__(256) void k3_final(
    const float2* __restrict__ part, const float* __restrict__ cterm,
    float* __restrict__ out)
{
    const int t = blockIdx.x * 256 + threadIdx.x;   // 0..8191
    const int b = t >> 9, i = t & 511;
    float s = 0.f, sp = 0.f;
    #pragma unroll
    for (int jc = 0; jc < JCH; ++jc) {
        const float2 v = part[(size_t)(((b << 5) + jc) << 9) + i];
        s  += v.x;
        sp += v.y;
    }
    out[t] = sp / s + *cterm;
}

extern "C" void kernel_launch(void* const* d_in, const int* in_sizes, int n_in,
                              void* d_out, int out_size, void* d_ws, size_t ws_size,
                              hipStream_t stream) {
    const float* x    = (const float*)d_in[0];
    const float* Wl   = (const float*)d_in[1];
    const float* bl   = (const float*)d_in[2];
    const float* Wr   = (const float*)d_in[3];
    const float* br   = (const float*)d_in[4];
    const float* att  = (const float*)d_in[5];
    const float* bias = (const float*)d_in[6];
    const float* Wf   = (const float*)d_in[7];
    const float* bf   = (const float*)d_in[8];
    float* out = (float*)d_out;

    unsigned char* ws = (unsigned char*)d_ws;
    unsigned int* uh   = (unsigned int*)ws;                     // ROWS*32 u32 (1 MB)
    unsigned int* vh   = uh + (size_t)ROWS * 32;                // ROWS*32 u32 (1 MB)
    float2*       part = (float2*)(vh + (size_t)ROWS * 32);     // B*JCH*NN float2 (2 MB)
    float2*       epj  = part + (size_t)BB * JCH * NN;          // ROWS float2 (64 KB)
    unsigned int* sgnh = (unsigned int*)(epj + ROWS);           // 32
    float*        ctp  = (float*)(sgnh + 32);                   // 1

    k1_transform<<<ROWS / RB, 256, 0, stream>>>(x, Wl, bl, Wr, br, att, bias, Wf, bf,
                                                uh, vh, epj, sgnh, ctp);
    k2_attn<<<BB * JCH, 512, 0, stream>>>(uh, vh, epj, sgnh, part);
    k3_final<<<ROWS / 256, 256, 0, stream>>>(part, ctp, out);
}